// Round 10
// baseline (459.179 us; speedup 1.0000x reference)
//
#include <hip/hip_runtime.h>
#include <math.h>

#define NCLS 40
#define BSZ 32          // dst nodes per bucket
#define BCAP 768        // slots per bucket (avg fill 512, P(overflow) ~ 1e-27)
#define NBR 128         // radix blocks; passes A and C share edge ranges

using f16x8 = __attribute__((ext_vector_type(8))) _Float16;
using f16x2 = __attribute__((ext_vector_type(2))) _Float16;
using f32x4 = __attribute__((ext_vector_type(4))) float;

// ---- pass A: per-block bucket histogram (LDS only; no global atomics) ----
// R9 post-mortem: 1.6M global atomic RMWs ran at ~8.7/cycle chip-wide = 74us
// floor. This radix build does ZERO global atomics.
__global__ __launch_bounds__(256) void radix_hist(const int* __restrict__ ei,
    int* __restrict__ hist, int e, int nbk) {
  extern __shared__ int h[];
  int t = threadIdx.x, b = blockIdx.x;
  for (int i = t; i < nbk; i += 256) h[i] = 0;
  __syncthreads();
  int per = (e + NBR - 1) / NBR;
  int lo = b * per, hi = min(e, lo + per);
  for (int i = lo + t; i < hi; i += 256)
    atomicAdd(&h[((unsigned)ei[e + i]) >> 5], 1);
  __syncthreads();
  for (int i = t; i < nbk; i += 256) hist[b * nbk + i] = h[i];
}

// ---- pass B: base[b][k] = k*BCAP + prefix_{b'<b} hist[b'][k]; cntb[k] ----
__global__ __launch_bounds__(256) void radix_scan(const int* __restrict__ hist,
    int* __restrict__ base, int* __restrict__ cntb, int nbk) {
  __shared__ int sh[NBR * 64];       // 32 KB tile: 128 blocks x 64 buckets
  int t = threadIdx.x;
  int k0 = blockIdx.x * 64;
  for (int i = t; i < NBR * 64; i += 256) {
    int bb = i >> 6, kk = k0 + (i & 63);
    sh[i] = (kk < nbk) ? hist[bb * nbk + kk] : 0;
  }
  __syncthreads();
  if (t < 64) {
    int k = k0 + t;
    if (k < nbk) {
      int a = k * BCAP;
      for (int bb = 0; bb < NBR; bb++) {   // serial column prefix, own bank
        int v = sh[bb * 64 + t];
        sh[bb * 64 + t] = a;
        a += v;
      }
      cntb[k] = min(a - k * BCAP, BCAP);
    }
  }
  __syncthreads();
  for (int i = t; i < NBR * 64; i += 256) {
    int bb = i >> 6, kk = k0 + (i & 63);
    if (kk < nbk) base[bb * nbk + kk] = sh[i];
  }
}

// ---- pass C: deterministic placement via LDS cursors (no global atomics).
// Per-(block,bucket) slots are consecutive (~4 records = 32B runs) -> writes
// cluster into lines; placement order is deterministic.
__global__ __launch_bounds__(256) void radix_place(const int* __restrict__ ei,
    const float* __restrict__ ew, const int* __restrict__ base,
    int2* __restrict__ bedge, int e, int nbk) {
  extern __shared__ int cur[];
  int t = threadIdx.x, b = blockIdx.x;
  for (int i = t; i < nbk; i += 256) cur[i] = base[b * nbk + i];
  __syncthreads();
  int per = (e + NBR - 1) / NBR;
  int lo = b * per, hi = min(e, lo + per);
  for (int i = lo + t; i < hi; i += 256) {
    int d = ei[e + i];
    int k = ((unsigned)d) >> 5;
    int pos = atomicAdd(&cur[k], 1);         // LDS atomic: fast, local
    if (pos < (k + 1) * BCAP)                // overflow guard (never in practice)
      bedge[pos] = make_int2(ei[i] | ((d & 31) << 20), __float_as_int(ew[i]));
  }
}

// ---------------- weight transpose + fp16 convert ----------------
__global__ void convert_wt(const float* __restrict__ W, _Float16* __restrict__ Wt) {
  int c = blockIdx.x;
  int k = threadIdx.x;
  Wt[c * 128 + k] = (_Float16)W[k * 128 + c];
}

// ------- MFMA GEMM: Y[n,128](f16) = A[n,128] @ W  (Wt = W^T, f16) -------
template<bool A32>
__global__ __launch_bounds__(256) void gemm_f16(const void* __restrict__ Av,
    const _Float16* __restrict__ Wt, _Float16* __restrict__ Y, int n) {
  __shared__ _Float16 Ys[64][136];   // bounce for coalesced stores
  int t = threadIdx.x;
  int wv = t >> 6, l = t & 63;
  int r0 = blockIdx.x * 64 + wv * 16;
  int arow = r0 + (l & 15);
  int kq = (l >> 4) * 8;
  bool rowok = arow < n;
  f32x4 acc[8] = {};
  for (int kc = 0; kc < 128; kc += 32) {
    f16x8 a = {};
    if (rowok) {
      if constexpr (A32) {
        const float* xp = (const float*)Av + (size_t)arow * 128 + kc + kq;
        float4 u0 = *(const float4*)xp;
        float4 u1 = *(const float4*)(xp + 4);
        a[0] = (_Float16)u0.x; a[1] = (_Float16)u0.y;
        a[2] = (_Float16)u0.z; a[3] = (_Float16)u0.w;
        a[4] = (_Float16)u1.x; a[5] = (_Float16)u1.y;
        a[6] = (_Float16)u1.z; a[7] = (_Float16)u1.w;
      } else {
        a = *(const f16x8*)((const _Float16*)Av + (size_t)arow * 128 + kc + kq);
      }
    }
    #pragma unroll
    for (int j = 0; j < 8; j++) {
      f16x8 b = *(const f16x8*)(Wt + (size_t)(j * 16 + (l & 15)) * 128 + kc + kq);
      acc[j] = __builtin_amdgcn_mfma_f32_16x16x32_f16(a, b, acc[j], 0, 0, 0);
    }
  }
  #pragma unroll
  for (int j = 0; j < 8; j++)
    #pragma unroll
    for (int i = 0; i < 4; i++)
      Ys[wv * 16 + (l >> 4) * 4 + i][j * 16 + (l & 15)] = (_Float16)acc[j][i];
  __syncthreads();
  int r = t >> 2;
  int c0 = (t & 3) * 32;
  int grow = blockIdx.x * 64 + r;
  if (grow < n) {
    #pragma unroll
    for (int i = 0; i < 4; i++) {
      f16x8 v = *(const f16x8*)&Ys[r][c0 + i * 8];
      *(f16x8*)(Y + (size_t)grow * 128 + c0 + i * 8) = v;
    }
  }
}

// -- fused bucket-sort + SpMM + self + bias + ReLU: H = relu(Y + A Y + b) --
__global__ __launch_bounds__(256) void spmm_sort_relu(const _Float16* __restrict__ Y,
    const int* __restrict__ cntb, const int2* __restrict__ bedge,
    const float* __restrict__ bias, _Float16* __restrict__ H, int n) {
  __shared__ int2 tmp[BCAP];          // 6 KB sorted edge image
  __shared__ int hist[BSZ], lpref[BSZ + 1], cur[BSZ];
  int t = threadIdx.x;
  int b = blockIdx.x;
  int cnt = cntb[b];
  if (t < BSZ) hist[t] = 0;
  __syncthreads();
  for (int i = t; i < cnt; i += 256)
    atomicAdd(&hist[(unsigned)bedge[b * BCAP + i].x >> 20], 1);
  __syncthreads();
  if (t == 0) {
    int a = 0;
    #pragma unroll
    for (int j = 0; j < BSZ; j++) { int v = hist[j]; lpref[j] = a; cur[j] = a; a += v; }
    lpref[BSZ] = a;
  }
  __syncthreads();
  for (int i = t; i < cnt; i += 256) {
    int2 r = bedge[b * BCAP + i];
    int dl = (unsigned)r.x >> 20;
    int pos = atomicAdd(&cur[dl], 1);
    tmp[pos] = make_int2(r.x & 0xFFFFF, r.y);   // strip dst-local bits
  }
  __syncthreads();
  int wv = t >> 6, lane = t & 63;
  int c = lane * 2;                   // 2 channels/lane -> 256B/wave gathers
  const _Float16* Yc = Y + c;
  for (int q = 0; q < 8; q++) {
    int dl = wv * 8 + q;              // wave handles 8 consecutive local nodes
    int node = b * BSZ + dl;
    if (node >= n) continue;
    int e0 = lpref[dl], e1 = lpref[dl + 1];
    float ax0 = 0.f, ay0 = 0.f, ax1 = 0.f, ay1 = 0.f;
    float ax2 = 0.f, ay2 = 0.f, ax3 = 0.f, ay3 = 0.f;
    int e = e0;
    for (; e + 3 < e1; e += 4) {      // 4 gathers in flight
      int2 p0 = tmp[e], p1 = tmp[e + 1], p2 = tmp[e + 2], p3 = tmp[e + 3];
      f16x2 v0 = *(const f16x2*)(Yc + (size_t)p0.x * 128);
      f16x2 v1 = *(const f16x2*)(Yc + (size_t)p1.x * 128);
      f16x2 v2 = *(const f16x2*)(Yc + (size_t)p2.x * 128);
      f16x2 v3 = *(const f16x2*)(Yc + (size_t)p3.x * 128);
      float w0 = __int_as_float(p0.y), w1 = __int_as_float(p1.y);
      float w2 = __int_as_float(p2.y), w3 = __int_as_float(p3.y);
      ax0 = fmaf(w0, (float)v0.x, ax0); ay0 = fmaf(w0, (float)v0.y, ay0);
      ax1 = fmaf(w1, (float)v1.x, ax1); ay1 = fmaf(w1, (float)v1.y, ay1);
      ax2 = fmaf(w2, (float)v2.x, ax2); ay2 = fmaf(w2, (float)v2.y, ay2);
      ax3 = fmaf(w3, (float)v3.x, ax3); ay3 = fmaf(w3, (float)v3.y, ay3);
    }
    for (; e < e1; e++) {
      int2 p0 = tmp[e];
      f16x2 v0 = *(const f16x2*)(Yc + (size_t)p0.x * 128);
      float w0 = __int_as_float(p0.y);
      ax0 = fmaf(w0, (float)v0.x, ax0); ay0 = fmaf(w0, (float)v0.y, ay0);
    }
    f16x2 yv = *(const f16x2*)(Yc + (size_t)node * 128);
    float2 bv = *(const float2*)(bias + c);
    float zx = (float)yv.x + (ax0 + ax1) + (ax2 + ax3) + bv.x;
    float zy = (float)yv.y + (ay0 + ay1) + (ay2 + ay3) + bv.y;
    f16x2 o;
    o.x = (_Float16)fmaxf(zx, 0.f);
    o.y = (_Float16)fmaxf(zy, 0.f);
    *(f16x2*)(H + (size_t)node * 128 + c) = o;
  }
}

// -------- FC over concat(h1,h2)(f16) + log_softmax (fp32 compute) --------
__global__ __launch_bounds__(256) void fc_lsm(const _Float16* __restrict__ H1,
    const _Float16* __restrict__ H2, const float* __restrict__ Wfc,
    const float* __restrict__ bfc, float* __restrict__ out, int n) {
  __shared__ float Wl[256 * NCLS];        // 40 KB, [k][c] layout
  __shared__ float Hs[64][132];           // 33 KB, transposed chunk Hs[k][r]
  int t = threadIdx.x;
  for (int i = t; i < 256 * NCLS; i += 256) Wl[i] = Wfc[i];
  int tx = t & 7, ty = t >> 3;            // tx: 5-col group (8x5=40), ty: 4-row group
  int row0 = blockIdx.x * 128;
  float acc[4][5] = {};
  for (int kc = 0; kc < 256; kc += 64) {
    {
      int r = t & 127;
      int half = t >> 7;
      int row = row0 + r;
      const _Float16* src = (kc < 128)
          ? (H1 + (size_t)row * 128 + kc + half * 32)
          : (H2 + (size_t)row * 128 + (kc - 128) + half * 32);
      if (row < n) {
        #pragma unroll
        for (int i = 0; i < 4; i++) {
          f16x8 v = ((const f16x8*)src)[i];
          #pragma unroll
          for (int q = 0; q < 8; q++) Hs[half * 32 + i * 8 + q][r] = (float)v[q];
        }
      } else {
        #pragma unroll
        for (int k = 0; k < 32; k++) Hs[half * 32 + k][r] = 0.f;
      }
    }
    __syncthreads();
    #pragma unroll 4
    for (int k = 0; k < 64; k++) {
      float4 a = *(const float4*)&Hs[k][ty * 4];
      const float* wrow = &Wl[(kc + k) * NCLS + tx * 5];
      float b_[5];
      #pragma unroll
      for (int j = 0; j < 5; j++) b_[j] = wrow[j];
      #pragma unroll
      for (int j = 0; j < 5; j++) {
        acc[0][j] = fmaf(a.x, b_[j], acc[0][j]);
        acc[1][j] = fmaf(a.y, b_[j], acc[1][j]);
        acc[2][j] = fmaf(a.z, b_[j], acc[2][j]);
        acc[3][j] = fmaf(a.w, b_[j], acc[3][j]);
      }
    }
    __syncthreads();
  }
  int c0 = tx * 5;
  float bv[5];
  #pragma unroll
  for (int j = 0; j < 5; j++) bv[j] = bfc[c0 + j];
  #pragma unroll
  for (int i = 0; i < 4; i++) {
    float lg[5];
    #pragma unroll
    for (int j = 0; j < 5; j++) lg[j] = acc[i][j] + bv[j];
    float m = lg[0];
    #pragma unroll
    for (int j = 1; j < 5; j++) m = fmaxf(m, lg[j]);
    m = fmaxf(m, __shfl_xor(m, 1));
    m = fmaxf(m, __shfl_xor(m, 2));
    m = fmaxf(m, __shfl_xor(m, 4));       // 8 lanes (same ty) own one row's 40 cols
    float ssum = 0.f;
    #pragma unroll
    for (int j = 0; j < 5; j++) ssum += __expf(lg[j] - m);
    ssum += __shfl_xor(ssum, 1);
    ssum += __shfl_xor(ssum, 2);
    ssum += __shfl_xor(ssum, 4);
    float lse = m + __logf(ssum);
    int row = row0 + ty * 4 + i;
    if (row < n) {
      #pragma unroll
      for (int j = 0; j < 5; j++) out[(size_t)row * NCLS + c0 + j] = lg[j] - lse;
    }
  }
}

extern "C" void kernel_launch(void* const* d_in, const int* in_sizes, int n_in,
                              void* d_out, int out_size, void* d_ws, size_t ws_size,
                              hipStream_t stream) {
  const float* x   = (const float*)d_in[0];
  const int*   ei  = (const int*)d_in[1];
  const float* ew  = (const float*)d_in[2];
  const float* W1  = (const float*)d_in[3];
  const float* b1  = (const float*)d_in[4];
  const float* W2  = (const float*)d_in[5];
  const float* b2  = (const float*)d_in[6];
  const float* Wfc = (const float*)d_in[7];
  const float* bfc = (const float*)d_in[8];
  float* out = (float*)d_out;
  int n = in_sizes[0] / 128;     // 100000
  int e = in_sizes[2];           // 1600000
  int nbk = (n + BSZ - 1) / BSZ; // 3125 buckets

  // workspace partition (~75 MB)
  char* ws = (char*)d_ws;
  size_t off = 0;
  auto alloc = [&](size_t bytes) -> void* {
    void* p = ws + off; off += (bytes + 255) & ~(size_t)255; return p;
  };
  int*      hist  = (int*)alloc((size_t)NBR * nbk * 4);
  int*      base  = (int*)alloc((size_t)NBR * nbk * 4);
  int*      cntb  = (int*)alloc((size_t)nbk * 4);
  int2*     bedge = (int2*)alloc((size_t)nbk * BCAP * 8);
  _Float16* w1t   = (_Float16*)alloc(128 * 128 * 2);
  _Float16* w2t   = (_Float16*)alloc(128 * 128 * 2);
  _Float16* y     = (_Float16*)alloc((size_t)n * 128 * 2);
  _Float16* h1    = (_Float16*)alloc((size_t)n * 128 * 2);
  _Float16* h2    = (_Float16*)alloc((size_t)n * 128 * 2);

  size_t dynls = (size_t)nbk * 4;   // 12.5 KB dynamic LDS for hist/cursors

  // radix bucket build (zero global atomics)
  radix_hist<<<NBR, 256, dynls, stream>>>(ei, hist, e, nbk);
  radix_scan<<<(nbk + 63) / 64, 256, 0, stream>>>(hist, base, cntb, nbk);
  radix_place<<<NBR, 256, dynls, stream>>>(ei, ew, base, bedge, e, nbk);

  // weight converts
  convert_wt<<<128, 128, 0, stream>>>(W1, w1t);
  convert_wt<<<128, 128, 0, stream>>>(W2, w2t);

  int gb = (n + 63) / 64;
  // layer 1: y = x@W1 ; h1 = relu(y + A y + b1)   (x fp32 read fused)
  gemm_f16<true><<<gb, 256, 0, stream>>>((const void*)x, w1t, y, n);
  spmm_sort_relu<<<nbk, 256, 0, stream>>>(y, cntb, bedge, b1, h1, n);
  // layer 2: y = h1@W2 ; h2 = relu(y + A y + b2)
  gemm_f16<false><<<gb, 256, 0, stream>>>((const void*)h1, w2t, y, n);
  spmm_sort_relu<<<nbk, 256, 0, stream>>>(y, cntb, bedge, b2, h2, n);
  // FC + log_softmax
  fc_lsm<<<(n + 127) / 128, 256, 0, stream>>>(h1, h2, Wfc, bfc, out, n);
}